// Round 1
// baseline (1117.468 us; speedup 1.0000x reference)
//
#include <hip/hip_runtime.h>

// ---------------- types / helpers ----------------
typedef unsigned short u16;
typedef u16    u16x8 __attribute__((ext_vector_type(8)));
typedef __bf16 bf16x8 __attribute__((ext_vector_type(8)));
typedef float  f32x4 __attribute__((ext_vector_type(4)));

#define BS  512
#define DIM 1024
#define HID 2048
#define NSTEPS 20

__device__ __forceinline__ u16 f2b(float x) {             // f32 -> bf16 bits, RNE
    unsigned u = __float_as_uint(x);
    return (u16)((u + 0x7FFFu + ((u >> 16) & 1u)) >> 16);
}
__device__ __forceinline__ float b2f(u16 h) { return __uint_as_float(((unsigned)h) << 16); }

__device__ __forceinline__ float fast_tanh(float x) {
    float ax = fabsf(x);
    float e  = __expf(2.0f * ax);
    float t  = 1.0f - 2.0f / (e + 1.0f);
    return copysignf(t, x);
}

#define MFMA16(a, b, c) __builtin_amdgcn_mfma_f32_16x16x32_bf16( \
    __builtin_bit_cast(bf16x8, (a)), __builtin_bit_cast(bf16x8, (b)), (c), 0, 0, 0)

// ---------------- prep kernels ----------------
// src: [R][C] f32 row-major  ->  dh/dl: [C][R] bf16 (hi/lo split), i.e. transposed
__global__ void transpose_split(const float* __restrict__ src, int R, int C,
                                u16* __restrict__ dh, u16* __restrict__ dl) {
    __shared__ u16 lh[32][33];
    __shared__ u16 ll[32][33];
    int tx = threadIdx.x & 31, ty = threadIdx.x >> 5;   // 32 x 8
    int r0 = blockIdx.y * 32, c0 = blockIdx.x * 32;
#pragma unroll
    for (int i = 0; i < 4; ++i) {
        int r = ty + i * 8;
        float v = src[(size_t)(r0 + r) * C + c0 + tx];
        u16 h = f2b(v);
        lh[r][tx] = h;
        ll[r][tx] = f2b(v - b2f(h));
    }
    __syncthreads();
#pragma unroll
    for (int i = 0; i < 4; ++i) {
        int r = ty + i * 8;                              // output row = input col
        dh[(size_t)(c0 + r) * R + r0 + tx] = lh[tx][r];
        dl[(size_t)(c0 + r) * R + r0 + tx] = ll[tx][r];
    }
}

__global__ void z_init(const float* __restrict__ z0, float* __restrict__ Zf,
                       u16* __restrict__ Zh, u16* __restrict__ Zl, int n) {
    int i = blockIdx.x * blockDim.x + threadIdx.x;
    if (i < n) {
        float v = z0[i];
        Zf[i] = v;
        u16 h = f2b(v);
        Zh[i] = h;
        Zl[i] = f2b(v - b2f(h));
    }
}

// ---------------- fused GEMM step kernel ----------------
// C_tile(32x64) = A(M x K, split hi/lo, row-major) @ B^T stored as [NTOT][K] (split hi/lo)
// EPI==1: out = tanh(acc + bias + ti*wt)        -> Oh/Ol (bf16 split), leading dim NTOT
// EPI==2: zn  = Zin + h*(acc + bias)            -> Fout (f32) and optionally Oh/Ol
// 4 waves split K; LDS reduce; 3-term split-bf16 MFMA.
template <int K, int NTOT, int EPI>
__global__ __launch_bounds__(256) void gemm_step(
    const u16* __restrict__ Ah, const u16* __restrict__ Al,
    const u16* __restrict__ Bh, const u16* __restrict__ Bl,
    const float* __restrict__ bias, const float* __restrict__ wt,
    const float* __restrict__ t, int step,
    const float* Zin, float* Fout,
    u16* __restrict__ Oh, u16* __restrict__ Ol, int wsplit) {

    constexpr int KS = K / 4;                 // per-wave K slice
    const int w  = threadIdx.x >> 6;
    const int l  = threadIdx.x & 63;
    const int r  = l & 15;
    const int kq = (l >> 4) * 8;
    const int m0 = blockIdx.y * 32;
    const int n0 = blockIdx.x * 64;

    const u16* pAh = Ah + (size_t)(m0 + r) * K + w * KS + kq;
    const u16* pAl = Al + (size_t)(m0 + r) * K + w * KS + kq;
    const u16* pBh = Bh + (size_t)(n0 + r) * K + w * KS + kq;
    const u16* pBl = Bl + (size_t)(n0 + r) * K + w * KS + kq;

    f32x4 acc[2][4] = {};

    for (int kk = 0; kk < KS; kk += 32) {
        u16x8 ah0 = *(const u16x8*)(pAh + kk);
        u16x8 ah1 = *(const u16x8*)(pAh + 16 * K + kk);
        u16x8 al0 = *(const u16x8*)(pAl + kk);
        u16x8 al1 = *(const u16x8*)(pAl + 16 * K + kk);
        u16x8 bh[4], bl[4];
#pragma unroll
        for (int ni = 0; ni < 4; ++ni) {
            bh[ni] = *(const u16x8*)(pBh + (size_t)ni * 16 * K + kk);
            bl[ni] = *(const u16x8*)(pBl + (size_t)ni * 16 * K + kk);
        }
#pragma unroll
        for (int ni = 0; ni < 4; ++ni) {
            acc[0][ni] = MFMA16(ah0, bh[ni], acc[0][ni]);
            acc[0][ni] = MFMA16(ah0, bl[ni], acc[0][ni]);
            acc[0][ni] = MFMA16(al0, bh[ni], acc[0][ni]);
            acc[1][ni] = MFMA16(ah1, bh[ni], acc[1][ni]);
            acc[1][ni] = MFMA16(ah1, bl[ni], acc[1][ni]);
            acc[1][ni] = MFMA16(al1, bh[ni], acc[1][ni]);
        }
    }

    // ---- reduce 4 wave-partials via LDS ----
    __shared__ __align__(16) float red[4 * 32 * 64];
    float* myred = red + w * 2048;
    const int kq4 = (l >> 4) * 4;
#pragma unroll
    for (int mi = 0; mi < 2; ++mi)
#pragma unroll
        for (int ni = 0; ni < 4; ++ni)
#pragma unroll
            for (int j = 0; j < 4; ++j) {
                int row = mi * 16 + kq4 + j;
                int col = ni * 16 + r;
                myred[row * 64 + col] = acc[mi][ni][j];
            }
    __syncthreads();

    const int tid = threadIdx.x;
    const int er  = tid >> 3;            // 0..31
    const int ec  = (tid & 7) * 8;       // 0..56
    const int base = er * 64 + ec;
    f32x4 s0 = *(const f32x4*)&red[base];
    f32x4 s1 = *(const f32x4*)&red[base + 4];
#pragma unroll
    for (int ww = 1; ww < 4; ++ww) {
        s0 += *(const f32x4*)&red[ww * 2048 + base];
        s1 += *(const f32x4*)&red[ww * 2048 + base + 4];
    }
    float s[8];
#pragma unroll
    for (int j = 0; j < 4; ++j) { s[j] = s0[j]; s[4 + j] = s1[j]; }

    // ---- time-step params from t (device-correct) ----
    const int   seg  = step >> 1, sub = step & 1;
    const float t0   = t[seg], t1 = t[seg + 1];
    const float hseg = 0.5f * (t1 - t0);
    const float ti   = t0 + hseg * (float)sub;

    const int R = m0 + er;
    const int C = n0 + ec;

    if constexpr (EPI == 1) {
        u16x8 vh, vl;
#pragma unroll
        for (int j = 0; j < 8; ++j) {
            float u = s[j] + bias[C + j] + ti * wt[C + j];
            float v = fast_tanh(u);
            u16 hb = f2b(v);
            vh[j] = hb;
            vl[j] = f2b(v - b2f(hb));
        }
        *(u16x8*)(Oh + (size_t)R * NTOT + C) = vh;
        *(u16x8*)(Ol + (size_t)R * NTOT + C) = vl;
    } else {
        const float* zp = Zin + (size_t)R * NTOT + C;
        f32x4 z0v = *(const f32x4*)zp;
        f32x4 z1v = *(const f32x4*)(zp + 4);
        float zn[8];
#pragma unroll
        for (int j = 0; j < 8; ++j) {
            float f = s[j] + bias[C + j];
            float zi = (j < 4) ? z0v[j] : z1v[j - 4];
            zn[j] = zi + hseg * f;
        }
        f32x4 o0, o1;
#pragma unroll
        for (int j = 0; j < 4; ++j) { o0[j] = zn[j]; o1[j] = zn[4 + j]; }
        *(f32x4*)(Fout + (size_t)R * NTOT + C)     = o0;
        *(f32x4*)(Fout + (size_t)R * NTOT + C + 4) = o1;
        if (wsplit) {
            u16x8 vh, vl;
#pragma unroll
            for (int j = 0; j < 8; ++j) {
                u16 hb = f2b(zn[j]);
                vh[j] = hb;
                vl[j] = f2b(zn[j] - b2f(hb));
            }
            *(u16x8*)(Oh + (size_t)R * NTOT + C) = vh;
            *(u16x8*)(Ol + (size_t)R * NTOT + C) = vl;
        }
    }
}

// ---------------- launch ----------------
extern "C" void kernel_launch(void* const* d_in, const int* in_sizes, int n_in,
                              void* d_out, int out_size, void* d_ws, size_t ws_size,
                              hipStream_t stream) {
    const float* z0 = (const float*)d_in[0];
    const float* t  = (const float*)d_in[1];
    const float* W1 = (const float*)d_in[2];
    const float* b1 = (const float*)d_in[3];
    const float* wt = (const float*)d_in[4];
    const float* W2 = (const float*)d_in[5];
    const float* b2 = (const float*)d_in[6];

    char* ws = (char*)d_ws;
    // workspace layout (24 MB total)
    float* Zf  = (float*)(ws);                    // 2 MB   512x1024 f32
    u16*   Zh  = (u16*)(ws + (2u  << 20));        // 1 MB
    u16*   Zl  = (u16*)(ws + (3u  << 20));        // 1 MB
    u16*   Hh  = (u16*)(ws + (4u  << 20));        // 2 MB   512x2048 bf16
    u16*   Hl  = (u16*)(ws + (6u  << 20));        // 2 MB
    u16*   W1h = (u16*)(ws + (8u  << 20));        // 4 MB   [HID][DIM]
    u16*   W1l = (u16*)(ws + (12u << 20));        // 4 MB
    u16*   W2h = (u16*)(ws + (16u << 20));        // 4 MB   [DIM][HID]
    u16*   W2l = (u16*)(ws + (20u << 20));        // 4 MB

    // prep: transpose+split weights, split z0
    transpose_split<<<dim3(HID / 32, DIM / 32), 256, 0, stream>>>(W1, DIM, HID, W1h, W1l);
    transpose_split<<<dim3(DIM / 32, HID / 32), 256, 0, stream>>>(W2, HID, DIM, W2h, W2l);
    z_init<<<(BS * DIM) / 256, 256, 0, stream>>>(z0, Zf, Zh, Zl, BS * DIM);

    float* out = (float*)d_out;
    for (int step = 0; step < NSTEPS; ++step) {
        // H = tanh(Z @ W1 + b1 + ti*wt)
        gemm_step<DIM, HID, 1><<<dim3(HID / 64, BS / 32), 256, 0, stream>>>(
            Zh, Zl, W1h, W1l, b1, wt, t, step,
            nullptr, nullptr, Hh, Hl, 1);
        // Znew = Z + h*(H @ W2 + b2)
        const bool last = (step == NSTEPS - 1);
        gemm_step<HID, DIM, 2><<<dim3(DIM / 64, BS / 32), 256, 0, stream>>>(
            Hh, Hl, W2h, W2l, b2, nullptr, t, step,
            Zf, last ? out : Zf, Zh, Zl, last ? 0 : 1);
    }
}

// Round 4
// 1087.266 us; speedup vs baseline: 1.0278x; 1.0278x over previous
//
#include <hip/hip_runtime.h>

// ---------------- types / helpers ----------------
typedef unsigned short u16;
typedef u16    u16x8 __attribute__((ext_vector_type(8)));
typedef __bf16 bf16x8 __attribute__((ext_vector_type(8)));
typedef float  f32x4 __attribute__((ext_vector_type(4)));

#define BS  512
#define DIM 1024
#define HID 2048
#define NSTEPS 20

__device__ __forceinline__ u16 f2b(float x) {             // f32 -> bf16 bits, RNE
    unsigned u = __float_as_uint(x);
    return (u16)((u + 0x7FFFu + ((u >> 16) & 1u)) >> 16);
}
__device__ __forceinline__ float b2f(u16 h) { return __uint_as_float(((unsigned)h) << 16); }

__device__ __forceinline__ float fast_tanh(float x) {
    float ax = fabsf(x);
    float e  = __expf(2.0f * ax);
    float t  = 1.0f - 2.0f / (e + 1.0f);
    return copysignf(t, x);
}

#define MFMA16(a, b, c) __builtin_amdgcn_mfma_f32_16x16x32_bf16( \
    __builtin_bit_cast(bf16x8, (a)), __builtin_bit_cast(bf16x8, (b)), (c), 0, 0, 0)

// Frag-packed layout: chunk = 1KB = [64 lanes][8 bf16] holding a 16(row)x32(k)
// tile; lane l -> row (l&15), k-offset (l>>4)*8. Array: [frag][kstep][chunk].

// ---------------- prep kernels ----------------
// W: [K][N] f32 row-major -> frag-packed Dh/Dl as B-operand ([nf][ks][chunk])
__global__ __launch_bounds__(256) void pack_w(const float* __restrict__ W, int K, int N,
                                              u16* __restrict__ Dh, u16* __restrict__ Dl) {
    __shared__ float tile[32][65];
    const int t  = threadIdx.x;
    const int n0 = blockIdx.x * 64;
    const int k0 = blockIdx.y * 32;
#pragma unroll
    for (int i = 0; i < 8; ++i) {
        int idx = i * 256 + t;
        int ky = idx >> 6, nx = idx & 63;
        tile[ky][nx] = W[(size_t)(k0 + ky) * N + n0 + nx];
    }
    __syncthreads();
    const int lane = t & 63, nfl = t >> 6;
    const int r = lane & 15, q = lane >> 4;
    const int nl = nfl * 16 + r;
    u16x8 vh, vl;
#pragma unroll
    for (int j = 0; j < 8; ++j) {
        float v = tile[q * 8 + j][nl];
        u16 h = f2b(v);
        vh[j] = h;
        vl[j] = f2b(v - b2f(h));
    }
    const int KS = K >> 5;
    const size_t nf  = (size_t)(n0 >> 4) + nfl;
    const size_t off = (nf * KS + (k0 >> 5)) * 512 + lane * 8;
    *(u16x8*)(Dh + off) = vh;
    *(u16x8*)(Dl + off) = vl;
}

// z0 [512][1024] f32 -> Zf copy + frag-packed Zh/Zl as A-operand
__global__ __launch_bounds__(256) void pack_z(const float* __restrict__ z0,
                                              float* __restrict__ Zf,
                                              u16* __restrict__ Zh, u16* __restrict__ Zl) {
    const int gid  = blockIdx.x * 256 + threadIdx.x;  // 65536 total
    const int lane = gid & 63;
    const int cidx = gid >> 6;                        // 0..1023
    const int ks = cidx & 31;
    const int mf = cidx >> 5;                         // 0..31
    const int r = lane & 15, q = lane >> 4;
    const int row = mf * 16 + r;
    const int col = ks * 32 + q * 8;
    const float* src = z0 + (size_t)row * DIM + col;
    f32x4 a = *(const f32x4*)src;
    f32x4 b = *(const f32x4*)(src + 4);
    u16x8 vh, vl;
#pragma unroll
    for (int j = 0; j < 4; ++j) {
        u16 h = f2b(a[j]); vh[j] = h; vl[j] = f2b(a[j] - b2f(h));
        u16 h2 = f2b(b[j]); vh[4 + j] = h2; vl[4 + j] = f2b(b[j] - b2f(h2));
    }
    *(f32x4*)(Zf + (size_t)row * DIM + col)     = a;
    *(f32x4*)(Zf + (size_t)row * DIM + col + 4) = b;
    const size_t off = ((size_t)mf * 32 + ks) * 512 + lane * 8;
    *(u16x8*)(Zh + off) = vh;
    *(u16x8*)(Zl + off) = vl;
}

// ---------------- streaming frag-packed GEMM ----------------
// C[Mt][Nt] = A[Mt][Kt] @ B (B frag-packed as [nf][ks]); 3-term split bf16.
// Wave tile 32x32, wave grid WM x WN per block, grid = (Mt/32/WM)*(Nt/32/WN).
// EPI 1: H = tanh(acc + bias + ti*wt) -> Oh/Ol frag-packed (A-layout for next GEMM)
// EPI 2: zn = Zin + hseg*(acc + bias) -> Fout row-major f32 (+ packed Oh/Ol if wsplit)
template <int Mt, int Nt, int Kt, int WM, int WN, int EPI>
__global__ __launch_bounds__(WM * WN * 64, 1) void gemm_pk(
    const u16* __restrict__ Ah, const u16* __restrict__ Al,
    const u16* __restrict__ Bh, const u16* __restrict__ Bl,
    const float* __restrict__ bias, const float* __restrict__ wvec,
    const float* __restrict__ t, int step,
    const float* __restrict__ Zin, float* __restrict__ Fout,
    u16* __restrict__ Oh, u16* __restrict__ Ol, int wsplit) {

    constexpr int KSc = Kt / 32;          // K-chunks of this GEMM
    constexpr int KSo = Nt / 32;          // K-chunks of the packed output
    constexpr int BM  = Mt / (WM * 32);   // m-blocks in grid

    const int nwg = gridDim.x;
    const int bid = blockIdx.x;
    const int swz = (bid & 7) * (nwg >> 3) + (bid >> 3);  // XCD-contiguous
    const int bm  = swz % BM;
    const int bn  = swz / BM;                             // n-slice per XCD (L2-resident B)

    const int l  = threadIdx.x & 63;
    const int w  = threadIdx.x >> 6;
    const int wm = w / WN;
    const int wn = w % WN;

    const int mf0 = (bm * WM + wm) * 2;
    const int nf0 = (bn * WN + wn) * 2;

    constexpr size_t CS = 512;                 // u16 per chunk
    constexpr size_t MS = (size_t)KSc * CS;    // chunk stride between frags

    const u16* pAh = Ah + (size_t)mf0 * MS + l * 8;
    const u16* pAl = Al + (size_t)mf0 * MS + l * 8;
    const u16* pBh = Bh + (size_t)nf0 * MS + l * 8;
    const u16* pBl = Bl + (size_t)nf0 * MS + l * 8;

    f32x4 acc[2][2] = {};

#pragma unroll 4
    for (int ks = 0; ks < KSc; ++ks) {
        const size_t o = (size_t)ks * CS;
        u16x8 ah0 = *(const u16x8*)(pAh + o);
        u16x8 ah1 = *(const u16x8*)(pAh + MS + o);
        u16x8 al0 = *(const u16x8*)(pAl + o);
        u16x8 al1 = *(const u16x8*)(pAl + MS + o);
        u16x8 bh0 = *(const u16x8*)(pBh + o);
        u16x8 bh1 = *(const u16x8*)(pBh + MS + o);
        u16x8 bl0 = *(const u16x8*)(pBl + o);
        u16x8 bl1 = *(const u16x8*)(pBl + MS + o);

        acc[0][0] = MFMA16(ah0, bh0, acc[0][0]);
        acc[0][0] = MFMA16(ah0, bl0, acc[0][0]);
        acc[0][0] = MFMA16(al0, bh0, acc[0][0]);
        acc[0][1] = MFMA16(ah0, bh1, acc[0][1]);
        acc[0][1] = MFMA16(ah0, bl1, acc[0][1]);
        acc[0][1] = MFMA16(al0, bh1, acc[0][1]);
        acc[1][0] = MFMA16(ah1, bh0, acc[1][0]);
        acc[1][0] = MFMA16(ah1, bl0, acc[1][0]);
        acc[1][0] = MFMA16(al1, bh0, acc[1][0]);
        acc[1][1] = MFMA16(ah1, bh1, acc[1][1]);
        acc[1][1] = MFMA16(ah1, bl1, acc[1][1]);
        acc[1][1] = MFMA16(al1, bh1, acc[1][1]);
    }

    // ---- epilogue: per-wave 32x32 transpose through LDS ----
    __shared__ float lds[WM * WN][32 * 36];
    float* L = lds[w];
    const int r = l & 15, q = l >> 4;
#pragma unroll
    for (int mi = 0; mi < 2; ++mi)
#pragma unroll
        for (int ni = 0; ni < 2; ++ni)
#pragma unroll
            for (int j = 0; j < 4; ++j)
                L[(mi * 16 + q * 4 + j) * 36 + ni * 16 + r] = acc[mi][ni][j];
    __syncthreads();

    const int   seg  = step >> 1, sub = step & 1;
    const float t0   = t[seg], t1 = t[seg + 1];
    const float hseg = 0.5f * (t1 - t0);
    const float ti   = t0 + hseg * (float)sub;

    const int c0 = nf0 * 16 + q * 8;          // output column base for this lane
#pragma unroll
    for (int mi2 = 0; mi2 < 2; ++mi2) {
        const int mf = mf0 + mi2;
        f32x4 v0 = *(const f32x4*)&L[(mi2 * 16 + r) * 36 + q * 8];
        f32x4 v1 = *(const f32x4*)&L[(mi2 * 16 + r) * 36 + q * 8 + 4];
        float v[8];
#pragma unroll
        for (int j = 0; j < 4; ++j) { v[j] = v0[j]; v[4 + j] = v1[j]; }

        if constexpr (EPI == 1) {
            u16x8 vh, vl;
#pragma unroll
            for (int j = 0; j < 8; ++j) {
                float u  = v[j] + bias[c0 + j] + ti * wvec[c0 + j];
                float tv = fast_tanh(u);
                u16 hb = f2b(tv);
                vh[j] = hb;
                vl[j] = f2b(tv - b2f(hb));
            }
            const size_t off = ((size_t)mf * KSo + (nf0 >> 1)) * CS + l * 8;
            *(u16x8*)(Oh + off) = vh;
            *(u16x8*)(Ol + off) = vl;
        } else {
            const int    mg = mf * 16 + r;
            const float* zp = Zin + (size_t)mg * Nt + c0;
            f32x4 z0v = *(const f32x4*)zp;
            f32x4 z1v = *(const f32x4*)(zp + 4);
            float zn[8];
#pragma unroll
            for (int j = 0; j < 8; ++j) {
                float f  = v[j] + bias[c0 + j];
                float zi = (j < 4) ? z0v[j] : z1v[j - 4];
                zn[j] = zi + hseg * f;
            }
            f32x4 o0, o1;
#pragma unroll
            for (int j = 0; j < 4; ++j) { o0[j] = zn[j]; o1[j] = zn[4 + j]; }
            *(f32x4*)(Fout + (size_t)mg * Nt + c0)     = o0;
            *(f32x4*)(Fout + (size_t)mg * Nt + c0 + 4) = o1;
            if (wsplit) {
                u16x8 vh, vl;
#pragma unroll
                for (int j = 0; j < 8; ++j) {
                    u16 hb = f2b(zn[j]);
                    vh[j] = hb;
                    vl[j] = f2b(zn[j] - b2f(hb));
                }
                const size_t off = ((size_t)mf * KSo + (nf0 >> 1)) * CS + l * 8;
                *(u16x8*)(Oh + off) = vh;
                *(u16x8*)(Ol + off) = vl;
            }
        }
    }
}

// ---------------- launch ----------------
extern "C" void kernel_launch(void* const* d_in, const int* in_sizes, int n_in,
                              void* d_out, int out_size, void* d_ws, size_t ws_size,
                              hipStream_t stream) {
    const float* z0 = (const float*)d_in[0];
    const float* t  = (const float*)d_in[1];
    const float* W1 = (const float*)d_in[2];
    const float* b1 = (const float*)d_in[3];
    const float* wt = (const float*)d_in[4];
    const float* W2 = (const float*)d_in[5];
    const float* b2 = (const float*)d_in[6];

    char* ws = (char*)d_ws;
    float* Zf  = (float*)(ws);                    // 2 MB   512x1024 f32
    u16*   Zh  = (u16*)(ws + (2u  << 20));        // 1 MB   packed [32][32][512]
    u16*   Zl  = (u16*)(ws + (3u  << 20));        // 1 MB
    u16*   Hh  = (u16*)(ws + (4u  << 20));        // 2 MB   packed [32][64][512]
    u16*   Hl  = (u16*)(ws + (6u  << 20));        // 2 MB
    u16*   W1h = (u16*)(ws + (8u  << 20));        // 4 MB   packed [128][32][512]
    u16*   W1l = (u16*)(ws + (12u << 20));        // 4 MB
    u16*   W2h = (u16*)(ws + (16u << 20));        // 4 MB   packed [64][64][512]
    u16*   W2l = (u16*)(ws + (20u << 20));        // 4 MB

    pack_w<<<dim3(HID / 64, DIM / 32), 256, 0, stream>>>(W1, DIM, HID, W1h, W1l);
    pack_w<<<dim3(DIM / 64, HID / 32), 256, 0, stream>>>(W2, HID, DIM, W2h, W2l);
    pack_z<<<256, 256, 0, stream>>>(z0, Zf, Zh, Zl);

    float* out = (float*)d_out;
    for (int step = 0; step < NSTEPS; ++step) {
        // H = tanh(Z @ W1 + b1 + ti*wt)   (512x2048, K=1024)
        gemm_pk<BS, HID, DIM, 2, 2, 1><<<256, 256, 0, stream>>>(
            Zh, Zl, W1h, W1l, b1, wt, t, step,
            nullptr, nullptr, Hh, Hl, 1);
        // Znew = Z + h*(H @ W2 + b2)      (512x1024, K=2048)
        const bool last = (step == NSTEPS - 1);
        gemm_pk<BS, DIM, HID, 2, 2, 2><<<128, 256, 0, stream>>>(
            Hh, Hl, W2h, W2l, b2, nullptr, t, step,
            Zf, last ? out : Zf, Zh, Zl, last ? 0 : 1);
    }
}